// Round 7
// baseline (892.307 us; speedup 1.0000x reference)
//
#include <hip/hip_runtime.h>
#include <stdint.h>

#define GAS __attribute__((address_space(1)))
#define LAS __attribute__((address_space(3)))

typedef int v4i __attribute__((ext_vector_type(4)));

constexpr int Mdim = 8192;    // B*S = 4*2048
constexpr int Ndim = 16384;   // D_OUT
constexpr int Kdim = 4096;    // D_IN

__device__ __forceinline__ int pack4i8(int a, int b, int c, int d) {
    return (a & 255) | ((b & 255) << 8) | ((c & 255) << 16) | ((d & 255) << 24);
}

__device__ __forceinline__ int qz(float v, float inv) {
    return (int)fminf(fmaxf(rintf(v * inv), -128.0f), 127.0f);
}

// ---- pass 1: quantize x fp32 -> int8 (16 elems/thread) ----
__global__ void k_quant_x(const float* __restrict__ x, const float* __restrict__ asc,
                          int8_t* __restrict__ xq) {
    const int i = blockIdx.x * blockDim.x + threadIdx.x;
    const float inv = 1.0f / *asc;
    const float4* xv = (const float4*)x + (size_t)i * 4;
    float4 f0 = xv[0], f1 = xv[1], f2 = xv[2], f3 = xv[3];
    int4 o;
    o.x = pack4i8(qz(f0.x, inv), qz(f0.y, inv), qz(f0.z, inv), qz(f0.w, inv));
    o.y = pack4i8(qz(f1.x, inv), qz(f1.y, inv), qz(f1.z, inv), qz(f1.w, inv));
    o.z = pack4i8(qz(f2.x, inv), qz(f2.y, inv), qz(f2.z, inv), qz(f2.w, inv));
    o.w = pack4i8(qz(f3.x, inv), qz(f3.y, inv), qz(f3.z, inv), qz(f3.w, inv));
    ((int4*)xq)[i] = o;
}

// ---- pass 2: weight int32 (sign-extended int8) -> packed int8 ----
__global__ void k_conv_w(const int* __restrict__ w, int8_t* __restrict__ wq) {
    const int i = blockIdx.x * blockDim.x + threadIdx.x;
    const int4* wv = (const int4*)w + (size_t)i * 4;
    int4 a = wv[0], b = wv[1], c = wv[2], d = wv[3];
    int4 o;
    o.x = pack4i8(a.x, a.y, a.z, a.w);
    o.y = pack4i8(b.x, b.y, b.z, b.w);
    o.z = pack4i8(c.x, c.y, c.z, c.w);
    o.w = pack4i8(d.x, d.y, d.z, d.w);
    ((int4*)wq)[i] = o;
}

// ============================================================================
// pass 3 (main): 256x256, 8 waves, K-tile=128B, 2-deep dbuf (128 KiB LDS),
// 8 phases/iter — WITH ONE-PHASE-AHEAD FRAGMENT PREFETCH AT ZERO REG COST:
//   phase p = { stage 1 call ; [vmcnt(8) even] ; s_barrier ; sched_barrier ;
//               setprio(1) ; 16 MFMA on a[],b[] loaded during phase p-1,
//               INTERLEAVED (sgb MFMA4/DS1) with ds_reads that refill a[fi]
//               right after its last use (group fi) for phase p+1 ;
//               [even: 4 b-reads after last MFMA for next K-half] ;
//               setprio(0) ; sched_barrier }
//   -> LDS drain hides under the MFMA cluster; ONE barrier per phase;
//      compiler's counted lgkm wait at cluster entry finds data drained.
//   Regions: A(buf,ks)=buf*65536+ks*16384, B=+32768. Zero-conflict swizzle
//   (verified rounds 2-6) unchanged.
//   Ledger (iter j, t0=2j, t1=2j+1), stage 1 call/phase:
//     ph1 stA(b1k1<-t1)   ph2 stB(b1k1<-t1)   ph3 stA(b0k0<-t0+2)
//     ph4 stB(b0k0<-t0+2) ph5 stA(b0k1<-t0+2) ph6 stB(b0k1<-t0+2)
//     ph7 stA(b1k0<-t1+2) ph8 stB(b1k0<-t1+2)
//   vmcnt(8) at ph2/4/6/8 validates each region exactly 1 barrier before its
//   first (prefetch) read; stage->validate distance 4-5 phases (>> latency).
//   Every stage targets a region whose last read is >=1 barrier upstream.
//   Tail iter: stages only ph1/ph2; vmcnt peels 8/4/0.
// ============================================================================
constexpr int NT    = Kdim / 128;  // 32 K-tiles
constexpr int NITER = NT / 2;      // 16

#define SGB __builtin_amdgcn_sched_group_barrier
#define VM8  asm volatile("s_waitcnt vmcnt(8)"  ::: "memory")
#define VM4  asm volatile("s_waitcnt vmcnt(4)"  ::: "memory")
#define VM0  asm volatile("s_waitcnt vmcnt(0)"  ::: "memory")

// one phase. a/b hold operands loaded during the PREVIOUS phase.
#define PH(ACC0, DO_PFA, PFA_BASE, PFA_ROW, DO_PFB, PFB_BASE, STAGE_STMT, VM_STMT) \
  {                                                                            \
    STAGE_STMT;                                                                \
    VM_STMT;                                                                   \
    __builtin_amdgcn_s_barrier();                                              \
    __builtin_amdgcn_sched_barrier(0);                                         \
    __builtin_amdgcn_s_setprio(1);                                             \
    _Pragma("unroll")                                                          \
    for (int fi = 0; fi < 4; ++fi) {                                           \
      _Pragma("unroll")                                                        \
      for (int fj = 0; fj < 4; ++fj)                                           \
        acc[(ACC0) + fi][fj] = __builtin_amdgcn_mfma_i32_16x16x64_i8(          \
            a[fi], b[fj], acc[(ACC0) + fi][fj], 0, 0, 0);                      \
    }                                                                          \
    if (DO_PFA) {                                                              \
      _Pragma("unroll")                                                        \
      for (int f = 0; f < 4; ++f)                                              \
        a[f] = *(const v4i*)(lds + (PFA_BASE) + (PFA_ROW) + f * 1024);         \
    }                                                                          \
    if (DO_PFB) {                                                              \
      _Pragma("unroll")                                                        \
      for (int f = 0; f < 4; ++f)                                              \
        b[f] = *(const v4i*)(lds + (PFB_BASE) + browb + f * 1024);             \
    }                                                                          \
    SGB(0x8, 4, 0); SGB(0x100, 1, 0);                                          \
    SGB(0x8, 4, 0); SGB(0x100, 1, 0);                                          \
    SGB(0x8, 4, 0); SGB(0x100, 1, 0);                                          \
    SGB(0x8, 4, 0); SGB(0x100, 1, 0);                                          \
    if (DO_PFB) { SGB(0x100, 4, 0); }                                          \
    __builtin_amdgcn_s_setprio(0);                                             \
    __builtin_amdgcn_sched_barrier(0);                                         \
  }

__global__ __launch_bounds__(512, 2)
void k_gemm256(const int8_t* __restrict__ Aq, const int8_t* __restrict__ Bq,
               const float* __restrict__ wscale, const float* __restrict__ asc,
               const float* __restrict__ bias, float* __restrict__ out) {
    __shared__ __align__(16) int8_t lds[131072];
    const int tid = threadIdx.x, lane = tid & 63, w = tid >> 6;
    const int wm = w >> 2, wn = w & 3;              // 2M x 4N wave grid
    const int lrow = lane & 15, kgrp = lane >> 4;

    const int bid = blockIdx.x;                     // grid = 2048, %8 == 0
    const int swz = ((bid & 7) << 8) | (bid >> 3);  // bijective XCD swizzle
    const int mt = swz & 31, nt = swz >> 5;         // m fastest: share B panel
    const int m0 = mt << 8, n0 = nt << 8;

    // ---- staging geometry (verified 0-conflict, rounds 2-6) ----
    const int srow = tid >> 2;                      // row within 128-row unit
    const int scol = (((tid & 3) ^ ((tid >> 3) & 3)) << 4);
    const int8_t* rowA0 = Aq + (size_t)(m0 + srow) * Kdim + scol;
    const int8_t* rowB0 = Bq + (size_t)(n0 + srow) * Kdim + scol;
    const size_t rb1off = (size_t)128 * Kdim;
    const int dstoff = w << 10;                     // + HW lane*16

    auto stA = [&](int t, int ks) {
        int8_t* d = lds + ((t & 1) << 16) + (ks << 14) + dstoff;
        const int8_t* s = rowA0 + t * 128 + ks * 64;
        __builtin_amdgcn_global_load_lds((const GAS void*)s, (LAS void*)d, 16, 0, 0);
        __builtin_amdgcn_global_load_lds((const GAS void*)(s + rb1off), (LAS void*)(d + 8192), 16, 0, 0);
    };
    auto stB = [&](int t, int ks) {
        int8_t* d = lds + ((t & 1) << 16) + 32768 + (ks << 14) + dstoff;
        const int8_t* s = rowB0 + t * 128 + ks * 64;
        __builtin_amdgcn_global_load_lds((const GAS void*)s, (LAS void*)d, 16, 0, 0);
        __builtin_amdgcn_global_load_lds((const GAS void*)(s + rb1off), (LAS void*)(d + 8192), 16, 0, 0);
    };

    // ---- read-side addressing (verified conflict-free swizzle) ----
    const int kc = (kgrp ^ ((lrow >> 1) & 3)) << 4;
    const int arow0 = ((wm << 7) + lrow) * 64 + kc;        // h0 rows
    const int arow1 = ((wm << 7) + 64 + lrow) * 64 + kc;   // h1 rows
    const int browb = ((wn << 6) + lrow) * 64 + kc;

    v4i acc[8][4];
#pragma unroll
    for (int i = 0; i < 8; ++i)
#pragma unroll
        for (int j = 0; j < 4; ++j) acc[i][j] = (v4i){0, 0, 0, 0};

    v4i a[4], b[4];

    // prologue: stage (b0k0),(b0k1),(b1k0); validate (b0k0); preload frags.
    stA(0, 0); stB(0, 0); stA(0, 1); stB(0, 1); stA(1, 0); stB(1, 0);
    VM8;
    __builtin_amdgcn_s_barrier();
#pragma unroll
    for (int f = 0; f < 4; ++f)
        a[f] = *(const v4i*)(lds + arow0 + f * 1024);
#pragma unroll
    for (int f = 0; f < 4; ++f)
        b[f] = *(const v4i*)(lds + 32768 + browb + f * 1024);

    for (int j = 0; j < NITER - 1; ++j) {
        const int t0 = 2 * j, t1 = 2 * j + 1;
        PH(0, 1, 0,     arow1, 0, 0,      stA(t1, 1),     (void)0);  // ph1
        PH(4, 1, 16384, arow0, 1, 49152,  stB(t1, 1),     VM8);      // ph2
        PH(0, 1, 16384, arow1, 0, 0,      stA(t0 + 2, 0), (void)0);  // ph3
        PH(4, 1, 65536, arow0, 1, 98304,  stB(t0 + 2, 0), VM8);      // ph4
        PH(0, 1, 65536, arow1, 0, 0,      stA(t0 + 2, 1), (void)0);  // ph5
        PH(4, 1, 81920, arow0, 1, 114688, stB(t0 + 2, 1), VM8);      // ph6
        PH(0, 1, 81920, arow1, 0, 0,      stA(t1 + 2, 0), (void)0);  // ph7
        PH(4, 1, 0,     arow0, 1, 32768,  stB(t1 + 2, 0), VM8);      // ph8
    }

    // tail iter (tiles 30,31): stages only ph1/ph2; vmcnt peels 8/4/0.
    {
        PH(0, 1, 0,     arow1, 0, 0,      stA(31, 1), (void)0);      // ph1
        PH(4, 1, 16384, arow0, 1, 49152,  stB(31, 1), VM8);          // ph2
        PH(0, 1, 16384, arow1, 0, 0,      (void)0,    (void)0);      // ph3
        PH(4, 1, 65536, arow0, 1, 98304,  (void)0,    VM4);          // ph4
        PH(0, 1, 65536, arow1, 0, 0,      (void)0,    (void)0);      // ph5
        PH(4, 1, 81920, arow0, 1, 114688, (void)0,    VM0);          // ph6
        PH(0, 1, 81920, arow1, 0, 0,      (void)0,    (void)0);      // ph7
        // ph8: plain cluster, no prefetch, no stage
        __builtin_amdgcn_s_barrier();
        __builtin_amdgcn_sched_barrier(0);
        __builtin_amdgcn_s_setprio(1);
#pragma unroll
        for (int fi = 0; fi < 4; ++fi)
#pragma unroll
            for (int fj = 0; fj < 4; ++fj)
                acc[4 + fi][fj] = __builtin_amdgcn_mfma_i32_16x16x64_i8(
                    a[fi], b[fj], acc[4 + fi][fj], 0, 0, 0);
        __builtin_amdgcn_s_setprio(0);
    }

    // epilogue: y = i32 * (act_scale * wscale[n]) + bias[n]
    const float ascale = *asc;
#pragma unroll
    for (int fj = 0; fj < 4; ++fj) {
        const int col = n0 + (wn << 6) + fj * 16 + lrow;
        const float sc = ascale * wscale[col];
        const float bb = bias[col];
#pragma unroll
        for (int mi = 0; mi < 8; ++mi) {
            const int r0 = m0 + (wm << 7) + mi * 16 + (kgrp << 2);
            float* o = out + (size_t)r0 * Ndim + col;
#pragma unroll
            for (int q = 0; q < 4; ++q)
                o[(size_t)q * Ndim] = (float)acc[mi][fj][q] * sc + bb;
        }
    }
}

// ============================================================================
// fallback 128x128 kernel (only used if workspace is too small)
// ============================================================================
template <bool AQ, bool BQ>
__global__ __launch_bounds__(256)
void k_gemm(const int8_t* __restrict__ Aq, const float* __restrict__ Xf,
            const int8_t* __restrict__ Bq, const int* __restrict__ W32,
            const float* __restrict__ wscale, const float* __restrict__ asc,
            const float* __restrict__ bias, float* __restrict__ out) {
    constexpr int BM = 128, BN = 128, BK = 64;
    constexpr int KT = Kdim / BK;
    __shared__ __align__(16) int8_t As[2][BM * BK];
    __shared__ __align__(16) int8_t Bs[2][BN * BK];

    const int tid  = threadIdx.x;
    const int lane = tid & 63;
    const int wid  = tid >> 6;
    const int wm = wid >> 1, wn = wid & 1;
    const int lrow = lane & 15, kgrp = lane >> 4;

    const int cpx = gridDim.x >> 3;
    const int swz = ((int)blockIdx.x & 7) * cpx + ((int)blockIdx.x >> 3);
    const int mt = swz & (Mdim / BM - 1);
    const int nt = swz / (Mdim / BM);
    const int m0 = mt * BM, n0 = nt * BN;

    const float ascale = *asc;
    const float inv = 1.0f / ascale;

    v4i acc[4][4];
#pragma unroll
    for (int i = 0; i < 4; ++i)
#pragma unroll
        for (int j = 0; j < 4; ++j) acc[i][j] = (v4i){0, 0, 0, 0};

    auto stage = [&](int buf, int kt) {
        const int k0 = kt * BK;
        if constexpr (AQ) {
            int8_t* ldsp = &As[buf][wid << 10];
            const int8_t* g = Aq + (size_t)(m0 + (tid >> 2)) * Kdim + k0 + ((tid & 3) << 4);
            __builtin_amdgcn_global_load_lds((const GAS void*)g, (LAS void*)ldsp, 16, 0, 0);
            __builtin_amdgcn_global_load_lds((const GAS void*)(g + (size_t)64 * Kdim),
                                             (LAS void*)(ldsp + 4096), 16, 0, 0);
        } else {
            const int row = tid >> 1, cb = (tid & 1) << 5;
            const float4* src = (const float4*)(Xf + (size_t)(m0 + row) * Kdim + k0 + cb);
            int t[8];
#pragma unroll
            for (int j = 0; j < 8; ++j) {
                float4 f = src[j];
                t[j] = pack4i8(qz(f.x, inv), qz(f.y, inv), qz(f.z, inv), qz(f.w, inv));
            }
            int4* dst = (int4*)&As[buf][row * BK + cb];
            dst[0] = make_int4(t[0], t[1], t[2], t[3]);
            dst[1] = make_int4(t[4], t[5], t[6], t[7]);
        }
        if constexpr (BQ) {
            int8_t* ldsp = &Bs[buf][wid << 10];
            const int8_t* g = Bq + (size_t)(n0 + (tid >> 2)) * Kdim + k0 + ((tid & 3) << 4);
            __builtin_amdgcn_global_load_lds((const GAS void*)g, (LAS void*)ldsp, 16, 0, 0);
            __builtin_amdgcn_global_load_lds((const GAS void*)(g + (size_t)64 * Kdim),
                                             (LAS void*)(ldsp + 4096), 16, 0, 0);
        } else {
            const int row = tid >> 1, cb = (tid & 1) << 5;
            const int4* src = (const int4*)(W32 + (size_t)(n0 + row) * Kdim + k0 + cb);
            int t[8];
#pragma unroll
            for (int j = 0; j < 8; ++j) {
                int4 vv = src[j];
                t[j] = pack4i8(vv.x, vv.y, vv.z, vv.w);
            }
            int4* dst = (int4*)&Bs[buf][row * BK + cb];
            dst[0] = make_int4(t[0], t[1], t[2], t[3]);
            dst[1] = make_int4(t[4], t[5], t[6], t[7]);
        }
    };

    stage(0, 0);
    for (int kt = 0; kt < KT; ++kt) {
        const int cur = kt & 1;
        __syncthreads();
        if (kt + 1 < KT) stage(cur ^ 1, kt + 1);

        v4i a[4], b[4];
        const int koff = kgrp << 4;
#pragma unroll
        for (int i = 0; i < 4; ++i) {
            a[i] = *(const v4i*)&As[cur][(wm * 64 + i * 16 + lrow) * BK + koff];
            b[i] = *(const v4i*)&Bs[cur][(wn * 64 + i * 16 + lrow) * BK + koff];
        }
#pragma unroll
        for (int i = 0; i < 4; ++i)
#pragma unroll
            for (int j = 0; j < 4; ++j)
                acc[i][j] = __builtin_amdgcn_mfma_i32_16x16x64_i8(a[i], b[j], acc[i][j], 0, 0, 0);
    }

#pragma unroll
    for (int j = 0; j < 4; ++j) {
        const int col = n0 + wn * 64 + j * 16 + lrow;
        const float sc = ascale * wscale[col];
        const float bb = bias[col];
#pragma unroll
        for (int i = 0; i < 4; ++i) {
            const int r0 = m0 + wm * 64 + i * 16 + (kgrp << 2);
            float* o = out + (size_t)r0 * Ndim + col;
#pragma unroll
            for (int r = 0; r < 4; ++r)
                o[(size_t)r * Ndim] = (float)acc[i][j][r] * sc + bb;
        }
    }
}

extern "C" void kernel_launch(void* const* d_in, const int* in_sizes, int n_in,
                              void* d_out, int out_size, void* d_ws, size_t ws_size,
                              hipStream_t stream) {
    const float* x      = (const float*)d_in[0];
    const int*   w32    = (const int*)d_in[1];   // int8 values sign-extended to int32
    const float* wscale = (const float*)d_in[2];
    const float* asc    = (const float*)d_in[3];
    const float* bias   = (const float*)d_in[4];
    float* out = (float*)d_out;

    const size_t nx = (size_t)Mdim * Kdim;  // 33,554,432 B for x_int8
    const size_t nw = (size_t)Ndim * Kdim;  // 67,108,864 B for w_int8
    int8_t* xq = (int8_t*)d_ws;
    int8_t* wq = xq + nx;

    const bool haveX = ws_size >= nx;
    const bool haveW = ws_size >= nx + nw;

    if (haveX) k_quant_x<<<(int)(nx / 16 / 256), 256, 0, stream>>>(x, asc, xq);
    if (haveW) k_conv_w<<<(int)(nw / 16 / 256), 256, 0, stream>>>(w32, wq);

    if (haveW) {
        dim3 grid((Mdim / 256) * (Ndim / 256));  // 2048
        k_gemm256<<<grid, 512, 0, stream>>>(xq, wq, wscale, asc, bias, out);
    } else if (haveX) {
        dim3 grid((Mdim / 128) * (Ndim / 128));  // 8192
        k_gemm<true, false><<<grid, 256, 0, stream>>>(xq, x, wq, w32, wscale, asc, bias, out);
    } else {
        dim3 grid((Mdim / 128) * (Ndim / 128));
        k_gemm<false, false><<<grid, 256, 0, stream>>>(xq, x, wq, w32, wscale, asc, bias, out);
    }
}